// Round 1
// baseline (134.933 us; speedup 1.0000x reference)
//
#include <hip/hip_runtime.h>
#include <hip/hip_fp16.h>

#define BLOCK 256
#define MAIN_BLOCKS_NOF 4096     // fallback (no-filter) config
#define FBLOCK 1024              // filtered main: 1024 thr
#define FGRID 512                // 2 blocks per CU (256 CUs)
#define NWAVES (FBLOCK / 64)
#define QCAP 256                 // per-wave ring queue (int2); must hold 191

// Fused prep: packed atom record (x,y,z,[sigma_f16|sqrt(eps)_f16]) + cell id.
// Cell grid 8x8x4 (3+3+2 bits = 1 byte). Cell sizes L/8, L/8, L/4.
// Also zeroes out[0] (harness poisons d_out before every launch).
__global__ void lj_prep_kernel(const float* __restrict__ coords,
                               const float* __restrict__ sigma,
                               const float* __restrict__ eps,
                               const float* __restrict__ box,
                               float4* __restrict__ table,
                               unsigned char* __restrict__ cellg,
                               float* __restrict__ out,
                               int n_atoms) {
    int i = blockIdx.x * blockDim.x + threadIdx.x;
    if (i == 0) out[0] = 0.0f;   // stream-ordered before main's atomicAdd
    if (i >= n_atoms) return;
    float x = coords[3 * i + 0];
    float y = coords[3 * i + 1];
    float z = coords[3 * i + 2];
    float s  = sigma[i];
    float se = sqrtf(eps[i]);
    unsigned pack = (unsigned)__half_as_ushort(__float2half(s)) |
                    ((unsigned)__half_as_ushort(__float2half(se)) << 16);
    table[i] = make_float4(x, y, z, __uint_as_float(pack));

    float L0 = box[0], L1 = box[4], L2 = box[8];
    int cx = min((int)(x * (8.0f / L0)), 7); cx = max(cx, 0);
    int cy = min((int)(y * (8.0f / L1)), 7); cy = max(cy, 0);
    int cz = min((int)(z * (4.0f / L2)), 3); cz = max(cz, 0);
    cellg[i] = (unsigned char)(cx | (cy << 3) | (cz << 6));
}

__device__ __forceinline__ float lj_energy(float4 pi, float4 pj,
                                           float L0, float L1, float L2,
                                           float b0, float b1, float b2,
                                           float c2) {
    float dx = pi.x - pj.x;
    float dy = pi.y - pj.y;
    float dz = pi.z - pj.z;
    float sx = dx * b0; sx -= floorf(sx + 0.5f); dx = sx * L0;
    float sy = dy * b1; sy -= floorf(sy + 0.5f); dy = sy * L1;
    float sz = dz * b2; sz -= floorf(sz + 0.5f); dz = sz * L2;
    float r2 = dx * dx + dy * dy + dz * dz;

    unsigned packi = __float_as_uint(pi.w);
    unsigned packj = __float_as_uint(pj.w);
    float si  = __half2float(__ushort_as_half((unsigned short)(packi & 0xffffu)));
    float sj  = __half2float(__ushort_as_half((unsigned short)(packj & 0xffffu)));
    float sei = __half2float(__ushort_as_half((unsigned short)(packi >> 16)));
    float sej = __half2float(__ushort_as_half((unsigned short)(packj >> 16)));

    float sij   = (si + sj) * 0.5f;
    float epsij = sei * sej;            // sqrt(eps_i)*sqrt(eps_j)
    float ratio = (sij * sij) / r2;     // (sigma_ij/dr)^2
    float t     = ratio * ratio * ratio;
    float e     = 4.0f * epsij * t * (t - 1.0f);
    return (r2 <= c2) ? e : 0.0f;
}

__device__ __forceinline__ bool cell_near(unsigned ci, unsigned cj) {
    unsigned dcx = (ci - cj) & 7u;
    unsigned dcy = ((ci >> 3) - (cj >> 3)) & 7u;
    unsigned dcz = ((ci >> 6) - (cj >> 6)) & 3u;
    return (dcx <= 1u || dcx == 7u) &&
           (dcy <= 1u || dcy == 7u) &&
           (dcz <= 1u || dcz == 3u);
}

// 64-lane prefix population count of a ballot mask (2 VALU ops).
__device__ __forceinline__ int prefix_cnt(unsigned long long bal) {
    return (int)__builtin_amdgcn_mbcnt_hi(
        (unsigned)(bal >> 32),
        __builtin_amdgcn_mbcnt_lo((unsigned)bal, 0u));
}

// Filtered + compacted main (v2: occupancy-first):
//  - cell bytes read DIRECTLY from global (100 KB, fully L2-resident) —
//    no LDS staging. LDS holds only the 32 KB queue -> 2 blocks/CU.
//  - __launch_bounds__(1024, 8) caps VGPR <= 64 -> 8 waves/SIMD (was 4).
//  - 2 pairs/thread via int4 loads, prefetched 1 ahead
//  - survivors compacted via ballot + mbcnt into a per-wave LDS ring queue
//  - queue drained 64-at-a-time: gathers + LJ math at FULL lane density
__global__ __launch_bounds__(FBLOCK, 8) void lj_main_filtered(
        const int4* __restrict__ pairs4,
        const int2* __restrict__ pairs2,
        const float4* __restrict__ table,
        const unsigned char* __restrict__ cellg,
        const float* __restrict__ box,
        const int* __restrict__ cutoff,
        float* __restrict__ out,
        int n_atoms, int n4, int n_pairs) {
    __shared__ int2 queue_s[NWAVES][QCAP];   // 32 KB static
    int lane = threadIdx.x & 63;
    int wid  = threadIdx.x >> 6;
    int2* queue = queue_s[wid];

    const float L0 = box[0], L1 = box[4], L2 = box[8];
    const float b0 = 1.0f / L0, b1 = 1.0f / L1, b2 = 1.0f / L2;
    const float c  = (float)cutoff[0];
    const float c2 = c * c;
    // filter validity: cell sizes must be >= cutoff on every axis
    const bool use_filter = (c <= L0 * 0.125f) && (c <= L1 * 0.125f) &&
                            (c <= L2 * 0.25f);

    float acc = 0.0f;
    int qcount = 0, head = 0;

    int base = (blockIdx.x * NWAVES + wid) * 64;   // int4 units (n4 < 2^31)
    int step = (int)gridDim.x * NWAVES * 64;

    bool v = (base + lane) < n4;
    int4 pp = v ? pairs4[base + lane] : make_int4(0, 0, 0, 0);

    while (base < n4) {
        // prefetch next chunk (hides pair-stream HBM latency)
        int nbase = base + step;
        bool vn = (nbase + lane) < n4;
        int4 ppn = vn ? pairs4[nbase + lane] : make_int4(0, 0, 0, 0);

        // issue all 4 cell gathers up front (independent L2 hits)
        unsigned ca0 = cellg[pp.x];
        unsigned cb0 = cellg[pp.y];
        unsigned ca1 = cellg[pp.z];
        unsigned cb1 = cellg[pp.w];

        // pair 0
        bool near0 = v && (!use_filter || cell_near(ca0, cb0));
        unsigned long long bal0 = __ballot(near0);
        int pos0 = prefix_cnt(bal0);
        if (near0) queue[(head + qcount + pos0) & (QCAP - 1)] = make_int2(pp.x, pp.y);
        qcount += (int)__popcll(bal0);

        // pair 1
        bool near1 = v && (!use_filter || cell_near(ca1, cb1));
        unsigned long long bal1 = __ballot(near1);
        int pos1 = prefix_cnt(bal1);
        if (near1) queue[(head + qcount + pos1) & (QCAP - 1)] = make_int2(pp.z, pp.w);
        qcount += (int)__popcll(bal1);

        while (qcount >= 64) {   // wave-uniform
            int2 e = queue[(head + lane) & (QCAP - 1)];
            float4 pi = table[e.x];
            float4 pj = table[e.y];
            acc += lj_energy(pi, pj, L0, L1, L2, b0, b1, b2, c2);
            head = (head + 64) & (QCAP - 1);
            qcount -= 64;
        }

        base = nbase; pp = ppn; v = vn;
    }
    // drain remainder
    if (lane < qcount) {
        int2 e = queue[(head + lane) & (QCAP - 1)];
        float4 pi = table[e.x];
        float4 pj = table[e.y];
        acc += lj_energy(pi, pj, L0, L1, L2, b0, b1, b2, c2);
    }
    // odd tail pair (not covered by int4 view)
    if (blockIdx.x == 0 && threadIdx.x == 0 && (n_pairs & 1)) {
        int2 e = pairs2[n_pairs - 1];
        acc += lj_energy(table[e.x], table[e.y], L0, L1, L2, b0, b1, b2, c2);
    }

    // wave (64-lane) reduction
    for (int off = 32; off > 0; off >>= 1)
        acc += __shfl_down(acc, off, 64);

    __shared__ float wsum[NWAVES];
    if (lane == 0) wsum[wid] = acc;
    __syncthreads();
    if (threadIdx.x == 0) {
        float s = 0.0f;
        for (int w = 0; w < NWAVES; w++) s += wsum[w];
        atomicAdd(out, s);
    }
}

// Fallback main (R1 structure) if workspace can't hold the tables.
__global__ __launch_bounds__(BLOCK) void lj_main_kernel(
        const int2* __restrict__ pairs,
        const float4* __restrict__ table,
        const float* __restrict__ box,
        const int* __restrict__ cutoff,
        float* __restrict__ out,
        int n_pairs) {
    const float L0 = box[0], L1 = box[4], L2 = box[8];
    const float b0 = 1.0f / L0, b1 = 1.0f / L1, b2 = 1.0f / L2;
    const float c  = (float)cutoff[0];
    const float c2 = c * c;

    float acc = 0.0f;
    int tid = blockIdx.x * blockDim.x + threadIdx.x;
    int stride = gridDim.x * blockDim.x;
    for (int p = tid; p < n_pairs; p += stride) {
        int2 ij = pairs[p];
        float4 pi = table[ij.x];
        float4 pj = table[ij.y];
        acc += lj_energy(pi, pj, L0, L1, L2, b0, b1, b2, c2);
    }
    for (int off = 32; off > 0; off >>= 1)
        acc += __shfl_down(acc, off, 64);
    __shared__ float wsum[BLOCK / 64];
    int lane = threadIdx.x & 63;
    int wid  = threadIdx.x >> 6;
    if (lane == 0) wsum[wid] = acc;
    __syncthreads();
    if (threadIdx.x == 0) {
        float s = 0.0f;
        for (int w = 0; w < BLOCK / 64; w++) s += wsum[w];
        atomicAdd(out, s);
    }
}

extern "C" void kernel_launch(void* const* d_in, const int* in_sizes, int n_in,
                              void* d_out, int out_size, void* d_ws, size_t ws_size,
                              hipStream_t stream) {
    const float* coords = (const float*)d_in[0];
    const int*   pairsi = (const int*)d_in[1];
    const float* box    = (const float*)d_in[2];
    const float* sigma  = (const float*)d_in[3];
    const float* eps    = (const float*)d_in[4];
    const int*   cutoff = (const int*)d_in[5];
    int n_atoms = in_sizes[0] / 3;
    int n_pairs = in_sizes[1] / 2;
    float* out = (float*)d_out;

    size_t table_bytes = ((size_t)n_atoms * sizeof(float4) + 255) & ~(size_t)255;
    size_t cell_bytes  = (size_t)n_atoms;
    float4* table = (float4*)d_ws;
    unsigned char* cellg = (unsigned char*)d_ws + table_bytes;

    lj_prep_kernel<<<(n_atoms + 255) / 256, 256, 0, stream>>>(
        coords, sigma, eps, box, table, cellg, out, n_atoms);

    bool can_filter = (ws_size >= table_bytes + cell_bytes);

    if (can_filter) {
        lj_main_filtered<<<FGRID, FBLOCK, 0, stream>>>(
            (const int4*)pairsi, (const int2*)pairsi, table, cellg, box,
            cutoff, out, n_atoms, n_pairs / 2, n_pairs);
    } else {
        lj_main_kernel<<<MAIN_BLOCKS_NOF, BLOCK, 0, stream>>>(
            (const int2*)pairsi, table, box, cutoff, out, n_pairs);
    }
}

// Round 2
// 105.548 us; speedup vs baseline: 1.2784x; 1.2784x over previous
//
#include <hip/hip_runtime.h>
#include <hip/hip_fp16.h>

#define BLOCK 256
#define MAIN_BLOCKS_NOF 4096     // fallback (no-filter) config
#define FBLOCK 1024              // filtered main: 1024 thr, 1 block/CU
#define FGRID 256                // exactly one block per CU
#define NWAVES (FBLOCK / 64)
#define QCAP 256                 // per-wave ring queue (int2); must hold 191

// Fused prep: packed atom record (x,y,z,[sigma_f16|sqrt(eps)_f16]) + cell id.
// Cell grid 8x8x4 (3+3+2 bits = 1 byte). Cell sizes L/8, L/8, L/4.
// Also zeroes out[0] (harness poisons d_out before every launch).
__global__ void lj_prep_kernel(const float* __restrict__ coords,
                               const float* __restrict__ sigma,
                               const float* __restrict__ eps,
                               const float* __restrict__ box,
                               float4* __restrict__ table,
                               unsigned char* __restrict__ cellg,
                               float* __restrict__ out,
                               int n_atoms) {
    int i = blockIdx.x * blockDim.x + threadIdx.x;
    if (i == 0) out[0] = 0.0f;   // stream-ordered before main's atomicAdd
    if (i >= n_atoms) return;
    float x = coords[3 * i + 0];
    float y = coords[3 * i + 1];
    float z = coords[3 * i + 2];
    float s  = sigma[i];
    float se = sqrtf(eps[i]);
    unsigned pack = (unsigned)__half_as_ushort(__float2half(s)) |
                    ((unsigned)__half_as_ushort(__float2half(se)) << 16);
    table[i] = make_float4(x, y, z, __uint_as_float(pack));

    float L0 = box[0], L1 = box[4], L2 = box[8];
    int cx = min((int)(x * (8.0f / L0)), 7); cx = max(cx, 0);
    int cy = min((int)(y * (8.0f / L1)), 7); cy = max(cy, 0);
    int cz = min((int)(z * (4.0f / L2)), 3); cz = max(cz, 0);
    cellg[i] = (unsigned char)(cx | (cy << 3) | (cz << 6));
}

__device__ __forceinline__ float lj_energy(float4 pi, float4 pj,
                                           float L0, float L1, float L2,
                                           float b0, float b1, float b2,
                                           float c2) {
    float dx = pi.x - pj.x;
    float dy = pi.y - pj.y;
    float dz = pi.z - pj.z;
    float sx = dx * b0; sx -= floorf(sx + 0.5f); dx = sx * L0;
    float sy = dy * b1; sy -= floorf(sy + 0.5f); dy = sy * L1;
    float sz = dz * b2; sz -= floorf(sz + 0.5f); dz = sz * L2;
    float r2 = dx * dx + dy * dy + dz * dz;

    unsigned packi = __float_as_uint(pi.w);
    unsigned packj = __float_as_uint(pj.w);
    float si  = __half2float(__ushort_as_half((unsigned short)(packi & 0xffffu)));
    float sj  = __half2float(__ushort_as_half((unsigned short)(packj & 0xffffu)));
    float sei = __half2float(__ushort_as_half((unsigned short)(packi >> 16)));
    float sej = __half2float(__ushort_as_half((unsigned short)(packj >> 16)));

    float sij   = (si + sj) * 0.5f;
    float epsij = sei * sej;            // sqrt(eps_i)*sqrt(eps_j)
    float ratio = (sij * sij) / r2;     // (sigma_ij/dr)^2
    float t     = ratio * ratio * ratio;
    float e     = 4.0f * epsij * t * (t - 1.0f);
    return (r2 <= c2) ? e : 0.0f;
}

__device__ __forceinline__ bool cell_near(unsigned ci, unsigned cj) {
    unsigned dcx = (ci - cj) & 7u;
    unsigned dcy = ((ci >> 3) - (cj >> 3)) & 7u;
    unsigned dcz = ((ci >> 6) - (cj >> 6)) & 3u;
    return (dcx <= 1u || dcx == 7u) &&
           (dcy <= 1u || dcy == 7u) &&
           (dcz <= 1u || dcz == 3u);
}

// 64-lane prefix population count of a ballot mask (2 VALU ops).
__device__ __forceinline__ int prefix_cnt(unsigned long long bal) {
    return (int)__builtin_amdgcn_mbcnt_hi(
        (unsigned)(bal >> 32),
        __builtin_amdgcn_mbcnt_lo((unsigned)bal, 0u));
}

// Filtered + compacted main (v3: round-0 structure + deep pipelining):
//  - per-atom cell bytes staged in LDS (100 KB; 1 block/CU, 4 waves/SIMD —
//    v2 proved global cell gathers + 64-VGPR cap are a 2x regression)
//  - pair stream prefetched TWO chunks ahead (~2 iters > 900cy HBM latency)
//  - cell gathers pipelined ONE stage ahead (~120cy LDS latency hidden)
//  - survivors compacted via ballot+mbcnt into per-wave LDS ring queue,
//    drained 64-at-a-time at full lane density
__global__ __launch_bounds__(FBLOCK) void lj_main_filtered(
        const int4* __restrict__ pairs4,
        const int2* __restrict__ pairs2,
        const float4* __restrict__ table,
        const unsigned char* __restrict__ cellg,
        const float* __restrict__ box,
        const int* __restrict__ cutoff,
        float* __restrict__ out,
        int n_atoms, int n4, int n_pairs, int qoff) {
    extern __shared__ unsigned char lds[];
    unsigned char* cellLds = lds;
    int lane = threadIdx.x & 63;
    int wid  = threadIdx.x >> 6;
    int2* queue = (int2*)(lds + qoff) + wid * QCAP;

    // cooperative LDS fill of cell bytes, 16B per thread per iter
    int n16 = n_atoms >> 4;
    const uint4* src = (const uint4*)cellg;
    uint4* dst = (uint4*)cellLds;
    for (int k = threadIdx.x; k < n16; k += blockDim.x) dst[k] = src[k];
    for (int k = (n16 << 4) + threadIdx.x; k < n_atoms; k += blockDim.x)
        cellLds[k] = cellg[k];
    __syncthreads();

    const float L0 = box[0], L1 = box[4], L2 = box[8];
    const float b0 = 1.0f / L0, b1 = 1.0f / L1, b2 = 1.0f / L2;
    const float c  = (float)cutoff[0];
    const float c2 = c * c;
    // filter validity: cell sizes must be >= cutoff on every axis
    const bool use_filter = (c <= L0 * 0.125f) && (c <= L1 * 0.125f) &&
                            (c <= L2 * 0.25f);

    float acc = 0.0f;
    int qcount = 0, head = 0;

    long base = ((long)blockIdx.x * NWAVES + wid) * 64;   // int4 units
    long step = (long)gridDim.x * NWAVES * 64;

    // ---- pipeline prologue ----
    // chunk 0 (current): pairs + cell gathers
    bool v = (base + lane) < n4;
    int4 pp = v ? pairs4[base + lane] : make_int4(0, 0, 0, 0);
    // chunk 1 (next): pairs only
    long b1i = base + step;
    bool v1 = (b1i + lane) < n4;
    int4 pp1 = v1 ? pairs4[b1i + lane] : make_int4(0, 0, 0, 0);
    // cells for chunk 0
    unsigned ga = cellLds[pp.x];
    unsigned gb = cellLds[pp.y];
    unsigned gc = cellLds[pp.z];
    unsigned gd = cellLds[pp.w];

    while (base < n4) {
        // prefetch chunk n+2 pairs (HBM latency hidden across 2 iterations)
        long b2i = base + 2 * step;
        bool v2 = (b2i + lane) < n4;
        int4 pp2 = v2 ? pairs4[b2i + lane] : make_int4(0, 0, 0, 0);

        // gather cells for chunk n+1 (LDS latency hidden across 1 iteration)
        unsigned na = cellLds[pp1.x];
        unsigned nb = cellLds[pp1.y];
        unsigned nc = cellLds[pp1.z];
        unsigned nd = cellLds[pp1.w];

        // ballot + compact chunk n using cells gathered last iteration
        bool near0 = v && (!use_filter || cell_near(ga, gb));
        unsigned long long bal0 = __ballot(near0);
        int pos0 = prefix_cnt(bal0);
        if (near0) queue[(head + qcount + pos0) & (QCAP - 1)] = make_int2(pp.x, pp.y);
        qcount += (int)__popcll(bal0);

        bool near1 = v && (!use_filter || cell_near(gc, gd));
        unsigned long long bal1 = __ballot(near1);
        int pos1 = prefix_cnt(bal1);
        if (near1) queue[(head + qcount + pos1) & (QCAP - 1)] = make_int2(pp.z, pp.w);
        qcount += (int)__popcll(bal1);

        while (qcount >= 64) {   // wave-uniform
            int2 e = queue[(head + lane) & (QCAP - 1)];
            float4 pi = table[e.x];
            float4 pj = table[e.y];
            acc += lj_energy(pi, pj, L0, L1, L2, b0, b1, b2, c2);
            head = (head + 64) & (QCAP - 1);
            qcount -= 64;
        }

        // rotate pipeline
        base = b1i; b1i = b2i;
        pp = pp1; v = v1; pp1 = pp2; v1 = v2;
        ga = na; gb = nb; gc = nc; gd = nd;
    }
    // drain remainder
    if (lane < qcount) {
        int2 e = queue[(head + lane) & (QCAP - 1)];
        float4 pi = table[e.x];
        float4 pj = table[e.y];
        acc += lj_energy(pi, pj, L0, L1, L2, b0, b1, b2, c2);
    }
    // odd tail pair (not covered by int4 view)
    if (blockIdx.x == 0 && threadIdx.x == 0 && (n_pairs & 1)) {
        int2 e = pairs2[n_pairs - 1];
        acc += lj_energy(table[e.x], table[e.y], L0, L1, L2, b0, b1, b2, c2);
    }

    // wave (64-lane) reduction
    for (int off = 32; off > 0; off >>= 1)
        acc += __shfl_down(acc, off, 64);

    __shared__ float wsum[NWAVES];
    if (lane == 0) wsum[wid] = acc;
    __syncthreads();
    if (threadIdx.x == 0) {
        float s = 0.0f;
        for (int w = 0; w < NWAVES; w++) s += wsum[w];
        atomicAdd(out, s);
    }
}

// Fallback main (R1 structure) if workspace/LDS can't hold the tables.
__global__ __launch_bounds__(BLOCK) void lj_main_kernel(
        const int2* __restrict__ pairs,
        const float4* __restrict__ table,
        const float* __restrict__ box,
        const int* __restrict__ cutoff,
        float* __restrict__ out,
        int n_pairs) {
    const float L0 = box[0], L1 = box[4], L2 = box[8];
    const float b0 = 1.0f / L0, b1 = 1.0f / L1, b2 = 1.0f / L2;
    const float c  = (float)cutoff[0];
    const float c2 = c * c;

    float acc = 0.0f;
    int tid = blockIdx.x * blockDim.x + threadIdx.x;
    int stride = gridDim.x * blockDim.x;
    for (int p = tid; p < n_pairs; p += stride) {
        int2 ij = pairs[p];
        float4 pi = table[ij.x];
        float4 pj = table[ij.y];
        acc += lj_energy(pi, pj, L0, L1, L2, b0, b1, b2, c2);
    }
    for (int off = 32; off > 0; off >>= 1)
        acc += __shfl_down(acc, off, 64);
    __shared__ float wsum[BLOCK / 64];
    int lane = threadIdx.x & 63;
    int wid  = threadIdx.x >> 6;
    if (lane == 0) wsum[wid] = acc;
    __syncthreads();
    if (threadIdx.x == 0) {
        float s = 0.0f;
        for (int w = 0; w < BLOCK / 64; w++) s += wsum[w];
        atomicAdd(out, s);
    }
}

extern "C" void kernel_launch(void* const* d_in, const int* in_sizes, int n_in,
                              void* d_out, int out_size, void* d_ws, size_t ws_size,
                              hipStream_t stream) {
    const float* coords = (const float*)d_in[0];
    const int*   pairsi = (const int*)d_in[1];
    const float* box    = (const float*)d_in[2];
    const float* sigma  = (const float*)d_in[3];
    const float* eps    = (const float*)d_in[4];
    const int*   cutoff = (const int*)d_in[5];
    int n_atoms = in_sizes[0] / 3;
    int n_pairs = in_sizes[1] / 2;
    float* out = (float*)d_out;

    size_t table_bytes = ((size_t)n_atoms * sizeof(float4) + 255) & ~(size_t)255;
    size_t cell_bytes  = (size_t)n_atoms;
    float4* table = (float4*)d_ws;
    unsigned char* cellg = (unsigned char*)d_ws + table_bytes;

    int qoff = (n_atoms + 15) & ~15;
    int shmem = qoff + NWAVES * QCAP * (int)sizeof(int2);

    lj_prep_kernel<<<(n_atoms + 255) / 256, 256, 0, stream>>>(
        coords, sigma, eps, box, table, cellg, out, n_atoms);

    bool can_filter = (ws_size >= table_bytes + cell_bytes) &&
                      (shmem <= 160 * 1024 - 1024);

    if (can_filter) {
        static bool attr_set = false;  // host-side, idempotent, same every call
        if (!attr_set) {
            hipFuncSetAttribute((const void*)lj_main_filtered,
                                hipFuncAttributeMaxDynamicSharedMemorySize,
                                shmem);
            attr_set = true;
        }
        lj_main_filtered<<<FGRID, FBLOCK, shmem, stream>>>(
            (const int4*)pairsi, (const int2*)pairsi, table, cellg, box,
            cutoff, out, n_atoms, n_pairs / 2, n_pairs, qoff);
    } else {
        lj_main_kernel<<<MAIN_BLOCKS_NOF, BLOCK, 0, stream>>>(
            (const int2*)pairsi, table, box, cutoff, out, n_pairs);
    }
}